// Round 1
// baseline (18332.204 us; speedup 1.0000x reference)
//
#include <hip/hip_runtime.h>
#include <hip/hip_cooperative_groups.h>

namespace cg = cooperative_groups;

#define B_ 64
#define T_ 512
#define D_ 512
#define N_ 1024
#define G_ 4096   // 4*N

typedef _Float16 f16;
typedef __attribute__((ext_vector_type(8))) _Float16 f16x8;
typedef __attribute__((ext_vector_type(4))) _Float16 f16x4;
typedef __attribute__((ext_vector_type(4))) float f32x4_t;

static __device__ __forceinline__ f32x4_t mfma16(f16x8 a, f16x8 b, f32x4_t c) {
    return __builtin_amdgcn_mfma_f32_16x16x32_f16(a, b, c, 0, 0, 0);
}

// ---------------------------------------------------------------------------
// Phase 0: WxT[g][d] = (f16) W[d][g]   for d in [0,512), g in [0,4096)
// 64x64 LDS tile transpose, coalesced both sides.
// ---------------------------------------------------------------------------
__global__ __launch_bounds__(256) void k_transpose_wx(const float* __restrict__ W,
                                                      f16* __restrict__ WxT) {
    __shared__ float tile[64][65];
    int bx = blockIdx.x;            // 8 d-tiles x 64 g-tiles
    int dt = bx >> 6, gt = bx & 63;
    int d0 = dt * 64, g0 = gt * 64;
    int tid = threadIdx.x;
    for (int e = tid; e < 4096; e += 256) {
        int r = e >> 6, c = e & 63;
        tile[r][c] = W[(size_t)(d0 + r) * G_ + (g0 + c)];
    }
    __syncthreads();
    for (int e = tid; e < 4096; e += 256) {
        int r = e >> 6, c = e & 63;
        WxT[(size_t)(g0 + r) * D_ + (d0 + c)] = (f16)tile[c][r];
    }
}

// ---------------------------------------------------------------------------
// Phase 1: xp[t][g][b] = (f16)( sum_d x[b][t][d]*W[d][g] + bias[g] )
// One WG per t. A (64 x 512, f16) staged in XOR-swizzled LDS.
// B-fragments read straight from WxT (L2-resident, 4 MB).
// Wave w owns g in [w*1024, w*1024+1024).
// ---------------------------------------------------------------------------
__global__ __launch_bounds__(256, 2) void k_xproj(const float* __restrict__ x,
                                                  const f16* __restrict__ WxT,
                                                  const float* __restrict__ bias,
                                                  f16* __restrict__ xp) {
    __shared__ __align__(16) f16 alds[64 * 512];   // 64 KB
    int t = blockIdx.x;
    int tid = threadIdx.x;
    int w = tid >> 6, l = tid & 63;

    // stage + convert A tile (b-major, d contiguous), 16B granules, XOR swizzle on b&7
    for (int ch = tid; ch < 4096; ch += 256) {
        int b  = ch >> 6;
        int d0 = (ch & 63) << 3;
        const float* px = x + ((size_t)b * T_ + t) * D_ + d0;
        float4 v0 = *(const float4*)px;
        float4 v1 = *(const float4*)(px + 4);
        f16x8 s;
        s[0] = (f16)v0.x; s[1] = (f16)v0.y; s[2] = (f16)v0.z; s[3] = (f16)v0.w;
        s[4] = (f16)v1.x; s[5] = (f16)v1.y; s[6] = (f16)v1.z; s[7] = (f16)v1.w;
        unsigned byteoff = ((unsigned)(b * 512 + d0) * 2u) ^ ((unsigned)(b & 7) << 4);
        *(f16x8*)((char*)alds + byteoff) = s;
    }
    __syncthreads();

    const int gw = w * 1024;
    const int qk = (l >> 4) << 3;      // 8*(lane/16) : k-offset within 32-wide k-step
    const int cc = l & 15;             // column within 16-wide tile

    for (int gtb = 0; gtb < 16; ++gtb) {
        f32x4_t acc[4][4];             // [gl][mb]
        #pragma unroll
        for (int a = 0; a < 4; ++a)
            #pragma unroll
            for (int m = 0; m < 4; ++m) acc[a][m] = f32x4_t{0.f, 0.f, 0.f, 0.f};

        for (int ks = 0; ks < 16; ++ks) {
            f16x8 afr[4];
            #pragma unroll
            for (int mb = 0; mb < 4; ++mb) {
                int b = mb * 16 + cc;
                int d = ks * 32 + qk;
                unsigned byteoff = ((unsigned)(b * 512 + d) * 2u) ^ ((unsigned)(b & 7) << 4);
                afr[mb] = *(const f16x8*)((const char*)alds + byteoff);
            }
            #pragma unroll
            for (int gl = 0; gl < 4; ++gl) {
                int g = gw + (gtb * 4 + gl) * 16 + cc;
                f16x8 bfr = *(const f16x8*)(WxT + (size_t)g * D_ + ks * 32 + qk);
                #pragma unroll
                for (int mb = 0; mb < 4; ++mb)
                    acc[gl][mb] = mfma16(afr[mb], bfr, acc[gl][mb]);
            }
        }
        // epilogue: xp[t][g][b], 4 consecutive b per lane-reg quad -> 8B stores
        #pragma unroll
        for (int gl = 0; gl < 4; ++gl) {
            int g = gw + (gtb * 4 + gl) * 16 + cc;
            float bg = bias[g];
            #pragma unroll
            for (int mb = 0; mb < 4; ++mb) {
                int b0 = mb * 16 + ((l >> 4) << 2);
                f16x4 sv;
                sv[0] = (f16)(acc[gl][mb][0] + bg);
                sv[1] = (f16)(acc[gl][mb][1] + bg);
                sv[2] = (f16)(acc[gl][mb][2] + bg);
                sv[3] = (f16)(acc[gl][mb][3] + bg);
                *(f16x4*)(xp + ((size_t)t * G_ + g) * B_ + b0) = sv;
            }
        }
    }
}

// ---------------------------------------------------------------------------
// Phase 2: persistent recurrence. 256 WGs x 256 threads (1 WG/CU).
// WG wg owns h-columns n0..n0+3 (16 gate columns: i/j/f/o quads).
// Wh slice lives in LDS in B-fragment order for all 512 steps.
// h double-buffer in global memory, stored in A-fragment order:
//   hbuf[buf][mb][ks][lane][i] = h[16*mb + (lane&15)][32*ks + 8*(lane>>4) + i]
// ---------------------------------------------------------------------------
__global__ __launch_bounds__(256, 1) void k_recur(const float* __restrict__ W,
                                                  const f16* __restrict__ xp,
                                                  f16* __restrict__ hbuf,
                                                  float* __restrict__ out) {
    __shared__ __align__(16) f16 wlds[16384];   // 32 KB: [ks(32)][lane(64)][i(8)]
    __shared__ float glds[4][16][16];           // per-wave gates tile
    cg::grid_group grid = cg::this_grid();

    int wg  = blockIdx.x;
    int tid = threadIdx.x;
    int w   = tid >> 6, l = tid & 63;
    int n0  = wg << 2;

    // load + convert this WG's Wh slice into LDS (fragment order)
    for (int idx = tid; idx < 16384; idx += 256) {
        int ks = idx >> 9, rem = idx & 511, ln = rem >> 3, i = rem & 7;
        int k  = ks * 32 + ((ln >> 4) << 3) + i;        // 0..1023
        int c  = ln & 15;
        int gc = n0 + (c & 3) + ((c >> 2) << 10);       // i/j/f/o quad packing
        wlds[idx] = (f16)W[(size_t)(D_ + k) * G_ + gc];
    }
    // zero h buffer 0 (grid-strided; only first 64 WGs participate)
    {
        int gtid = wg * 256 + tid;
        ushort4 z = make_ushort4(0, 0, 0, 0);
        for (int idx = gtid; idx < 16384; idx += 256 * 256)
            ((ushort4*)hbuf)[idx] = z;
    }
    float cst = 0.f;
    const int b_e = (w << 4) + (l & 15);   // this thread's batch for elementwise
    const int n_e = n0 + (l >> 4);         // this thread's h column
    const int cc  = l & 15;
    const int gc  = n0 + (cc & 3) + ((cc >> 2) << 10);
    const int b0i = (w << 4) + ((l >> 4) << 2);
    const size_t hw_off = ((size_t)(w << 14)) + (((size_t)n_e >> 5) << 9) +
                          ((((size_t)n_e >> 3) & 3) << 7) + ((size_t)(l & 15) << 3) + (n_e & 7);

    grid.sync();

    int cur = 0;
    for (int t = 0; t < T_; ++t) {
        // prefetch x_proj contribution (4 consecutive batches, 8B)
        f16x4 xv = *(const f16x4*)(xp + ((size_t)t * G_ + gc) * B_ + b0i);

        const f16* hb = hbuf + cur * 65536 + w * 16384;
        f32x4_t acc0 = f32x4_t{0.f, 0.f, 0.f, 0.f};
        f32x4_t acc1 = f32x4_t{0.f, 0.f, 0.f, 0.f};
        #pragma unroll 4
        for (int ks = 0; ks < 32; ks += 2) {
            f16x8 a0 = *(const f16x8*)(hb + ks * 512 + l * 8);
            f16x8 b0 = *(const f16x8*)(wlds + ks * 512 + l * 8);
            f16x8 a1 = *(const f16x8*)(hb + (ks + 1) * 512 + l * 8);
            f16x8 b1 = *(const f16x8*)(wlds + (ks + 1) * 512 + l * 8);
            acc0 = mfma16(a0, b0, acc0);
            acc1 = mfma16(a1, b1, acc1);
        }
        f32x4_t acc = acc0 + acc1;
        acc[0] += (float)xv[0]; acc[1] += (float)xv[1];
        acc[2] += (float)xv[2]; acc[3] += (float)xv[3];

        // exchange gates within the wave via LDS
        int rq = (l >> 4) << 2;
        glds[w][rq + 0][cc] = acc[0];
        glds[w][rq + 1][cc] = acc[1];
        glds[w][rq + 2][cc] = acc[2];
        glds[w][rq + 3][cc] = acc[3];
        __syncthreads();

        float gi = glds[w][l & 15][(l >> 4) + 0];
        float gj = glds[w][l & 15][(l >> 4) + 4];
        float gf = glds[w][l & 15][(l >> 4) + 8];
        float go = glds[w][l & 15][(l >> 4) + 12];

        float si = 1.f / (1.f + __expf(-gi));
        float tj = tanhf(gj);
        float sf = 1.f / (1.f + __expf(-(gf + 1.f)));
        float so = 1.f / (1.f + __expf(-go));
        cst = cst * sf + si * tj;
        float h = tanhf(cst) * so;

        out[((size_t)b_e * T_ + t) * N_ + n_e] = h;
        int nxt = cur ^ 1;
        hbuf[(size_t)nxt * 65536 + hw_off] = (f16)h;

        grid.sync();
        cur = nxt;
    }
}

// ---------------------------------------------------------------------------
extern "C" void kernel_launch(void* const* d_in, const int* in_sizes, int n_in,
                              void* d_out, int out_size, void* d_ws, size_t ws_size,
                              hipStream_t stream) {
    const float* x    = (const float*)d_in[0];
    const float* W    = (const float*)d_in[1];
    const float* bias = (const float*)d_in[2];
    float* out = (float*)d_out;

    char* ws = (char*)d_ws;
    f16* WxT  = (f16*)ws;                                        // 4 MB
    f16* xp   = (f16*)(ws + ((size_t)4 << 20));                  // 256 MB
    f16* hbuf = (f16*)(ws + ((size_t)4 << 20) + ((size_t)1 << 28)); // 256 KB

    size_t need = ((size_t)4 << 20) + ((size_t)1 << 28) + (size_t)2 * 65536 * 2;
    if (ws_size < need) {
        // not enough scratch: bail safely (will fail validation, not corrupt memory)
        hipMemsetAsync(d_out, 0, (size_t)out_size * sizeof(float), stream);
        return;
    }

    hipLaunchKernelGGL(k_transpose_wx, dim3(512), dim3(256), 0, stream, W, WxT);
    hipLaunchKernelGGL(k_xproj, dim3(512), dim3(256), 0, stream, x, WxT, bias, xp);

    const f16* xp_c = xp;
    void* args[] = { (void*)&W, (void*)&xp_c, (void*)&hbuf, (void*)&out };
    hipLaunchCooperativeKernel((void*)k_recur, dim3(256), dim3(256), args, 0, stream);
}

// Round 3
// 12755.579 us; speedup vs baseline: 1.4372x; 1.4372x over previous
//
#include <hip/hip_runtime.h>

#define B_ 64
#define T_ 512
#define D_ 512
#define N_ 1024
#define G_ 4096   // 4*N

typedef _Float16 f16;
typedef __attribute__((ext_vector_type(8))) _Float16 f16x8;
typedef __attribute__((ext_vector_type(4))) _Float16 f16x4;
typedef __attribute__((ext_vector_type(4))) float f32x4_t;
typedef unsigned long long u64;

static __device__ __forceinline__ f32x4_t mfma16(f16x8 a, f16x8 b, f32x4_t c) {
    return __builtin_amdgcn_mfma_f32_16x16x32_f16(a, b, c, 0, 0, 0);
}

// ---------------------------------------------------------------------------
// Phase 0: WxT[g][d] = (f16) W[d][g]   (validated in R1)
// ---------------------------------------------------------------------------
__global__ __launch_bounds__(256) void k_transpose_wx(const float* __restrict__ W,
                                                      f16* __restrict__ WxT) {
    __shared__ float tile[64][65];
    int bx = blockIdx.x;
    int dt = bx >> 6, gt = bx & 63;
    int d0 = dt * 64, g0 = gt * 64;
    int tid = threadIdx.x;
    for (int e = tid; e < 4096; e += 256) {
        int r = e >> 6, c = e & 63;
        tile[r][c] = W[(size_t)(d0 + r) * G_ + (g0 + c)];
    }
    __syncthreads();
    for (int e = tid; e < 4096; e += 256) {
        int r = e >> 6, c = e & 63;
        WxT[(size_t)(g0 + r) * D_ + (d0 + c)] = (f16)tile[c][r];
    }
}

// ---------------------------------------------------------------------------
// Phase 1: xp[t][g][b] = (f16)( x@Wx + bias )   (validated in R1)
// ---------------------------------------------------------------------------
__global__ __launch_bounds__(256, 2) void k_xproj(const float* __restrict__ x,
                                                  const f16* __restrict__ WxT,
                                                  const float* __restrict__ bias,
                                                  f16* __restrict__ xp) {
    __shared__ __align__(16) f16 alds[64 * 512];   // 64 KB
    int t = blockIdx.x;
    int tid = threadIdx.x;
    int w = tid >> 6, l = tid & 63;

    for (int ch = tid; ch < 4096; ch += 256) {
        int b  = ch >> 6;
        int d0 = (ch & 63) << 3;
        const float* px = x + ((size_t)b * T_ + t) * D_ + d0;
        float4 v0 = *(const float4*)px;
        float4 v1 = *(const float4*)(px + 4);
        f16x8 s;
        s[0] = (f16)v0.x; s[1] = (f16)v0.y; s[2] = (f16)v0.z; s[3] = (f16)v0.w;
        s[4] = (f16)v1.x; s[5] = (f16)v1.y; s[6] = (f16)v1.z; s[7] = (f16)v1.w;
        unsigned byteoff = ((unsigned)(b * 512 + d0) * 2u) ^ ((unsigned)(b & 7) << 4);
        *(f16x8*)((char*)alds + byteoff) = s;
    }
    __syncthreads();

    const int gw = w * 1024;
    const int qk = (l >> 4) << 3;
    const int cc = l & 15;

    for (int gtb = 0; gtb < 16; ++gtb) {
        f32x4_t acc[4][4];
        #pragma unroll
        for (int a = 0; a < 4; ++a)
            #pragma unroll
            for (int m = 0; m < 4; ++m) acc[a][m] = f32x4_t{0.f, 0.f, 0.f, 0.f};

        for (int ks = 0; ks < 16; ++ks) {
            f16x8 afr[4];
            #pragma unroll
            for (int mb = 0; mb < 4; ++mb) {
                int b = mb * 16 + cc;
                int d = ks * 32 + qk;
                unsigned byteoff = ((unsigned)(b * 512 + d) * 2u) ^ ((unsigned)(b & 7) << 4);
                afr[mb] = *(const f16x8*)((const char*)alds + byteoff);
            }
            #pragma unroll
            for (int gl = 0; gl < 4; ++gl) {
                int g = gw + (gtb * 4 + gl) * 16 + cc;
                f16x8 bfr = *(const f16x8*)(WxT + (size_t)g * D_ + ks * 32 + qk);
                #pragma unroll
                for (int mb = 0; mb < 4; ++mb)
                    acc[gl][mb] = mfma16(afr[mb], bfr, acc[gl][mb]);
            }
        }
        #pragma unroll
        for (int gl = 0; gl < 4; ++gl) {
            int g = gw + (gtb * 4 + gl) * 16 + cc;
            float bg = bias[g];
            #pragma unroll
            for (int mb = 0; mb < 4; ++mb) {
                int b0 = mb * 16 + ((l >> 4) << 2);
                f16x4 sv;
                sv[0] = (f16)(acc[gl][mb][0] + bg);
                sv[1] = (f16)(acc[gl][mb][1] + bg);
                sv[2] = (f16)(acc[gl][mb][2] + bg);
                sv[3] = (f16)(acc[gl][mb][3] + bg);
                *(f16x4*)(xp + ((size_t)t * G_ + g) * B_ + b0) = sv;
            }
        }
    }
}

// ---------------------------------------------------------------------------
// Phase 2: persistent recurrence, 4 independent batch groups of 64 WGs.
// WG (bg = wg>>6, ci = wg&63): batches [16bg,16bg+16) x h-cols [16ci,16ci+16).
// Wave w: K-slice [256w, 256w+256), all 64 gate cols (4 n-tiles).
// Wh slice (1024 x 64 gate cols) in LDS, B-fragment order: 128 KB.
// h exchange: Abuf[2][bg][ks32][lane64][i8] f16 in A-fragment order via
// 64-bit AGENT-scope atomics (LLC-coherent, no L2 staleness possible).
// Barrier: per-WG epoch flag; consumers poll their group's 64 flags
// (one per lane, single coalesced load per iteration).
// ---------------------------------------------------------------------------
__global__ __launch_bounds__(256, 1) void k_recur3(const float* __restrict__ W,
                                                   const f16* __restrict__ xp,
                                                   f16* __restrict__ Abuf,
                                                   unsigned* __restrict__ flags,
                                                   float* __restrict__ out) {
    __shared__ __align__(16) f16 wlds[65536];   // 128 KB: [ks32][nt4][lane64][i8]
    __shared__ float pacc[4][4][16][17];        // [kwave][ntile][batch][c15+pad]

    const int wg  = blockIdx.x;
    const int tid = threadIdx.x;
    const int w   = tid >> 6;
    const int l   = tid & 63;
    const int bg  = wg >> 6;
    const int ci  = wg & 63;

    const int lb    = l & 15;                   // local batch (elementwise)
    const int dh    = l >> 4;                   // 0..3
    const int nh    = ci * 16 + w * 4 + dh;     // this thread's h column
    const int bglob = bg * 16 + lb;

    // ---- stage Wh slice into LDS (B-fragment order), coalesced on gate cols ----
    for (int idx = tid; idx < 65536; idx += 256) {
        int gcl = idx & 63;                     // ty*16 + local col
        int k   = idx >> 6;                     // 0..1023
        int ty  = gcl >> 4, c = gcl & 15;
        float wv = W[(size_t)(D_ + k) * G_ + ty * 1024 + ci * 16 + c];
        int ks = k >> 5, i = k & 7, kq = (k >> 3) & 3;
        int nt = c >> 2, dcl = c & 3;
        int lane = (kq << 4) | (ty << 2) | dcl;
        wlds[(((ks * 4 + nt) * 64 + lane) << 3) + i] = (f16)wv;
    }

    // h slot addressing (A-fragment order). For fixed (ci,w,lb) the 4 dh-values
    // occupy 4 consecutive shorts at i0=(w&1)*4 of one (ks_h,lane_h) group.
    const int ks_h   = nh >> 5;
    const int lane_h = (((nh & 31) >> 3) << 4) | lb;
    char* const ab = (char*)Abuf;
    const size_t BUFB   = (size_t)4 * 32 * 64 * 16;  // 131072 bytes per copy
    const size_t grp_st = (((size_t)(bg * 32 + ks_h) * 64 + lane_h) << 4) + ((size_t)(w & 1) << 3);
    const size_t grp_ld = ((size_t)(bg * 32 + w * 8) * 64 + l) << 4;

    // ---- init: zero this WG's slots in buf0, publish epoch 1 ----
    if (dh == 0)
        __hip_atomic_store((u64*)(ab + grp_st), 0ull,
                           __ATOMIC_RELAXED, __HIP_MEMORY_SCOPE_AGENT);
    __builtin_amdgcn_fence(__ATOMIC_RELEASE, "agent");
    __syncthreads();   // also orders wlds staging before first use
    if (tid == 0)
        __hip_atomic_store(&flags[wg], 1u, __ATOMIC_RELEASE, __HIP_MEMORY_SCOPE_AGENT);

    unsigned* const gf = flags + bg * 64;
    float cst = 0.f;

    for (int t = 0; t < T_; ++t) {
        // wait until all 64 producers of this group published epoch t+1
        {
            const unsigned tgt = (unsigned)(t + 1);
            while (true) {
                unsigned v = __hip_atomic_load(&gf[l], __ATOMIC_RELAXED, __HIP_MEMORY_SCOPE_AGENT);
                if (__all(v >= tgt)) break;
            }
        }
        const int cur = t & 1;

        // A fragments: 16 x 8B agent-atomic loads (LLC)
        f16x8 af[8];
        {
            const char* pl = ab + (size_t)cur * BUFB + grp_ld;
            #pragma unroll
            for (int kk = 0; kk < 8; ++kk) {
                u64 lo = __hip_atomic_load((const u64*)(pl + kk * 1024),
                                           __ATOMIC_RELAXED, __HIP_MEMORY_SCOPE_AGENT);
                u64 hi = __hip_atomic_load((const u64*)(pl + kk * 1024 + 8),
                                           __ATOMIC_RELAXED, __HIP_MEMORY_SCOPE_AGENT);
                ulonglong2 u2; u2.x = lo; u2.y = hi;
                af[kk] = __builtin_bit_cast(f16x8, u2);
            }
        }

        // x-projection gate biases for (bglob, nh)
        f16 xg0 = xp[((size_t)t * G_ + (0 * 1024 + nh)) * B_ + bglob];
        f16 xg1 = xp[((size_t)t * G_ + (1 * 1024 + nh)) * B_ + bglob];
        f16 xg2 = xp[((size_t)t * G_ + (2 * 1024 + nh)) * B_ + bglob];
        f16 xg3 = xp[((size_t)t * G_ + (3 * 1024 + nh)) * B_ + bglob];

        // MFMA: 8 k-steps x 4 n-tiles, B from LDS
        f32x4_t acc[4];
        #pragma unroll
        for (int nt = 0; nt < 4; ++nt) acc[nt] = f32x4_t{0.f, 0.f, 0.f, 0.f};
        #pragma unroll
        for (int kk = 0; kk < 8; ++kk) {
            #pragma unroll
            for (int nt = 0; nt < 4; ++nt) {
                f16x8 bf = *(const f16x8*)(wlds + ((((w * 8 + kk) * 4 + nt) * 64 + l) << 3));
                acc[nt] = mfma16(af[kk], bf, acc[nt]);
            }
        }

        // cross-wave K-reduction via LDS
        {
            const int r0 = dh << 2;
            #pragma unroll
            for (int nt = 0; nt < 4; ++nt)
                #pragma unroll
                for (int j = 0; j < 4; ++j)
                    pacc[w][nt][r0 + j][l & 15] = acc[nt][j];
        }
        __syncthreads();

        float g0 = pacc[0][w][lb][0 * 4 + dh] + pacc[1][w][lb][0 * 4 + dh]
                 + pacc[2][w][lb][0 * 4 + dh] + pacc[3][w][lb][0 * 4 + dh] + (float)xg0;
        float g1 = pacc[0][w][lb][1 * 4 + dh] + pacc[1][w][lb][1 * 4 + dh]
                 + pacc[2][w][lb][1 * 4 + dh] + pacc[3][w][lb][1 * 4 + dh] + (float)xg1;
        float g2 = pacc[0][w][lb][2 * 4 + dh] + pacc[1][w][lb][2 * 4 + dh]
                 + pacc[2][w][lb][2 * 4 + dh] + pacc[3][w][lb][2 * 4 + dh] + (float)xg2;
        float g3 = pacc[0][w][lb][3 * 4 + dh] + pacc[1][w][lb][3 * 4 + dh]
                 + pacc[2][w][lb][3 * 4 + dh] + pacc[3][w][lb][3 * 4 + dh] + (float)xg3;

        float si = 1.f / (1.f + __expf(-g0));
        float tj = tanhf(g1);
        float sf = 1.f / (1.f + __expf(-(g2 + 1.f)));
        float so = 1.f / (1.f + __expf(-g3));
        cst = cst * sf + si * tj;
        float h = tanhf(cst) * so;

        out[((size_t)bglob * T_ + t) * N_ + nh] = h;

        // pack 4 h values (dh=0..3) into one 64-bit slot, store to next buffer
        {
            unsigned hu = (unsigned)__builtin_bit_cast(unsigned short, (f16)h);
            unsigned ot = __shfl_xor(hu, 16);
            unsigned dw = (dh & 1) ? ((ot & 0xffffu) | (hu << 16))
                                   : ((hu & 0xffffu) | (ot << 16));
            unsigned dw2 = __shfl_xor(dw, 32);
            if (dh == 0) {
                u64 val = (u64)dw | ((u64)dw2 << 32);
                __hip_atomic_store((u64*)(ab + (size_t)(cur ^ 1) * BUFB + grp_st), val,
                                   __ATOMIC_RELAXED, __HIP_MEMORY_SCOPE_AGENT);
            }
        }

        __builtin_amdgcn_fence(__ATOMIC_RELEASE, "agent");
        __syncthreads();
        if (tid == 0)
            __hip_atomic_store(&flags[wg], (unsigned)(t + 2),
                               __ATOMIC_RELEASE, __HIP_MEMORY_SCOPE_AGENT);
    }
}

// ---------------------------------------------------------------------------
extern "C" void kernel_launch(void* const* d_in, const int* in_sizes, int n_in,
                              void* d_out, int out_size, void* d_ws, size_t ws_size,
                              hipStream_t stream) {
    const float* x    = (const float*)d_in[0];
    const float* W    = (const float*)d_in[1];
    const float* bias = (const float*)d_in[2];
    float* out = (float*)d_out;

    // Layout: [0,4MB) = WxT (dead after k_xproj) OVERLAPPED by Abuf+flags
    // (used only by k_recur3, memset/written after k_xproj). [4MB, +256MB) = xp.
    char* ws = (char*)d_ws;
    f16*      WxT   = (f16*)ws;
    f16*      Abuf  = (f16*)ws;                          // 262144 B
    unsigned* flags = (unsigned*)(ws + 262144);          // 1024 B
    f16*      xp    = (f16*)(ws + ((size_t)4 << 20));    // 256 MB

    const size_t need = ((size_t)4 << 20) + ((size_t)1 << 28);
    if (ws_size < need) {
        hipMemsetAsync(d_out, 0, (size_t)out_size * sizeof(float), stream);
        return;
    }

    hipLaunchKernelGGL(k_transpose_wx, dim3(512), dim3(256), 0, stream, W, WxT);
    hipLaunchKernelGGL(k_xproj, dim3(512), dim3(256), 0, stream, x, WxT, bias, xp);

    // reset flags AFTER xproj (region overlaps WxT); re-executes on every
    // graph replay, so the epoch protocol starts from 0 deterministically.
    hipMemsetAsync(flags, 0, 1024, stream);

    const f16* xp_c = xp;
    void* args[] = { (void*)&W, (void*)&xp_c, (void*)&Abuf, (void*)&flags, (void*)&out };
    hipError_t e = hipLaunchCooperativeKernel((void*)k_recur3, dim3(256), dim3(256),
                                              args, 0, stream);
    if (e != hipSuccess) {
        // co-residency also holds under a normal launch: 148 KB LDS -> exactly
        // 1 WG/CU, grid 256 == CU count, nothing else running on the device.
        hipLaunchKernelGGL(k_recur3, dim3(256), dim3(256), 0, stream,
                           W, xp_c, Abuf, flags, out);
    }
}

// Round 4
// 3050.086 us; speedup vs baseline: 6.0104x; 4.1820x over previous
//
#include <hip/hip_runtime.h>

#define B_ 64
#define T_ 512
#define D_ 512
#define N_ 1024
#define G_ 4096   // 4*N

typedef _Float16 f16;
typedef __attribute__((ext_vector_type(8))) _Float16 f16x8;
typedef __attribute__((ext_vector_type(4))) _Float16 f16x4;
typedef __attribute__((ext_vector_type(4))) float f32x4_t;
typedef unsigned long long u64;

static __device__ __forceinline__ f32x4_t mfma16(f16x8 a, f16x8 b, f32x4_t c) {
    return __builtin_amdgcn_mfma_f32_16x16x32_f16(a, b, c, 0, 0, 0);
}

// ---------------------------------------------------------------------------
// Phase 0: WxT[g][d] = (f16) W[d][g]   (validated R1)
// ---------------------------------------------------------------------------
__global__ __launch_bounds__(256) void k_transpose_wx(const float* __restrict__ W,
                                                      f16* __restrict__ WxT) {
    __shared__ float tile[64][65];
    int bx = blockIdx.x;
    int dt = bx >> 6, gt = bx & 63;
    int d0 = dt * 64, g0 = gt * 64;
    int tid = threadIdx.x;
    for (int e = tid; e < 4096; e += 256) {
        int r = e >> 6, c = e & 63;
        tile[r][c] = W[(size_t)(d0 + r) * G_ + (g0 + c)];
    }
    __syncthreads();
    for (int e = tid; e < 4096; e += 256) {
        int r = e >> 6, c = e & 63;
        WxT[(size_t)(g0 + r) * D_ + (d0 + c)] = (f16)tile[c][r];
    }
}

// ---------------------------------------------------------------------------
// Phase 1: xp[t][g][b] = (f16)( x@Wx + bias )   (validated R1)
// ---------------------------------------------------------------------------
__global__ __launch_bounds__(256, 2) void k_xproj(const float* __restrict__ x,
                                                  const f16* __restrict__ WxT,
                                                  const float* __restrict__ bias,
                                                  f16* __restrict__ xp) {
    __shared__ __align__(16) f16 alds[64 * 512];   // 64 KB
    int t = blockIdx.x;
    int tid = threadIdx.x;
    int w = tid >> 6, l = tid & 63;

    for (int ch = tid; ch < 4096; ch += 256) {
        int b  = ch >> 6;
        int d0 = (ch & 63) << 3;
        const float* px = x + ((size_t)b * T_ + t) * D_ + d0;
        float4 v0 = *(const float4*)px;
        float4 v1 = *(const float4*)(px + 4);
        f16x8 s;
        s[0] = (f16)v0.x; s[1] = (f16)v0.y; s[2] = (f16)v0.z; s[3] = (f16)v0.w;
        s[4] = (f16)v1.x; s[5] = (f16)v1.y; s[6] = (f16)v1.z; s[7] = (f16)v1.w;
        unsigned byteoff = ((unsigned)(b * 512 + d0) * 2u) ^ ((unsigned)(b & 7) << 4);
        *(f16x8*)((char*)alds + byteoff) = s;
    }
    __syncthreads();

    const int gw = w * 1024;
    const int qk = (l >> 4) << 3;
    const int cc = l & 15;

    for (int gtb = 0; gtb < 16; ++gtb) {
        f32x4_t acc[4][4];
        #pragma unroll
        for (int a = 0; a < 4; ++a)
            #pragma unroll
            for (int m = 0; m < 4; ++m) acc[a][m] = f32x4_t{0.f, 0.f, 0.f, 0.f};

        for (int ks = 0; ks < 16; ++ks) {
            f16x8 afr[4];
            #pragma unroll
            for (int mb = 0; mb < 4; ++mb) {
                int b = mb * 16 + cc;
                int d = ks * 32 + qk;
                unsigned byteoff = ((unsigned)(b * 512 + d) * 2u) ^ ((unsigned)(b & 7) << 4);
                afr[mb] = *(const f16x8*)((const char*)alds + byteoff);
            }
            #pragma unroll
            for (int gl = 0; gl < 4; ++gl) {
                int g = gw + (gtb * 4 + gl) * 16 + cc;
                f16x8 bfr = *(const f16x8*)(WxT + (size_t)g * D_ + ks * 32 + qk);
                #pragma unroll
                for (int mb = 0; mb < 4; ++mb)
                    acc[gl][mb] = mfma16(afr[mb], bfr, acc[gl][mb]);
            }
        }
        #pragma unroll
        for (int gl = 0; gl < 4; ++gl) {
            int g = gw + (gtb * 4 + gl) * 16 + cc;
            float bg = bias[g];
            #pragma unroll
            for (int mb = 0; mb < 4; ++mb) {
                int b0 = mb * 16 + ((l >> 4) << 2);
                f16x4 sv;
                sv[0] = (f16)(acc[gl][mb][0] + bg);
                sv[1] = (f16)(acc[gl][mb][1] + bg);
                sv[2] = (f16)(acc[gl][mb][2] + bg);
                sv[3] = (f16)(acc[gl][mb][3] + bg);
                *(f16x4*)(xp + ((size_t)t * G_ + g) * B_ + b0) = sv;
            }
        }
    }
}

// ---------------------------------------------------------------------------
// Phase 2: persistent recurrence (structure validated R3).
// R4 delta: NO fences / NO release atomics in the loop -> no buffer_wbl2.
// All cross-WG traffic is sc0sc1 (LLC-coherent); ordering = vmcnt(0) ack at
// the LLC serialization point, then relaxed flag publish. Wave 0 polls alone.
// ---------------------------------------------------------------------------
__global__ __launch_bounds__(256, 1) void k_recur4(const float* __restrict__ W,
                                                   const f16* __restrict__ xp,
                                                   f16* __restrict__ Abuf,
                                                   unsigned* __restrict__ flags,
                                                   float* __restrict__ out) {
    __shared__ __align__(16) f16 wlds[65536];   // 128 KB: [ks32][nt4][lane64][i8]
    __shared__ float pacc[4][4][16][17];        // [kwave][ntile][batch][c15+pad]

    const int wg  = blockIdx.x;
    const int tid = threadIdx.x;
    const int w   = tid >> 6;
    const int l   = tid & 63;
    const int bg  = wg >> 6;
    const int ci  = wg & 63;

    const int lb    = l & 15;
    const int dh    = l >> 4;
    const int nh    = ci * 16 + w * 4 + dh;
    const int bglob = bg * 16 + lb;

    // ---- stage Wh slice into LDS (B-fragment order) ----
    for (int idx = tid; idx < 65536; idx += 256) {
        int gcl = idx & 63;
        int k   = idx >> 6;
        int ty  = gcl >> 4, c = gcl & 15;
        float wv = W[(size_t)(D_ + k) * G_ + ty * 1024 + ci * 16 + c];
        int ks = k >> 5, i = k & 7, kq = (k >> 3) & 3;
        int nt = c >> 2, dcl = c & 3;
        int lane = (kq << 4) | (ty << 2) | dcl;
        wlds[(((ks * 4 + nt) * 64 + lane) << 3) + i] = (f16)wv;
    }

    const int ks_h   = nh >> 5;
    const int lane_h = (((nh & 31) >> 3) << 4) | lb;
    char* const ab = (char*)Abuf;
    const size_t BUFB   = (size_t)4 * 32 * 64 * 16;  // 131072 B per copy
    const size_t grp_st = (((size_t)(bg * 32 + ks_h) * 64 + lane_h) << 4) + ((size_t)(w & 1) << 3);
    const size_t grp_ld = ((size_t)(bg * 32 + w * 8) * 64 + l) << 4;

    // ---- init: zero buf0 slots (LLC), ack, publish epoch 1 ----
    if (dh == 0)
        __hip_atomic_store((u64*)(ab + grp_st), 0ull,
                           __ATOMIC_RELAXED, __HIP_MEMORY_SCOPE_AGENT);
    asm volatile("s_waitcnt vmcnt(0)" ::: "memory");
    __syncthreads();   // also covers wlds staging
    if (tid == 0)
        __hip_atomic_store(&flags[wg], 1u, __ATOMIC_RELAXED, __HIP_MEMORY_SCOPE_AGENT);

    unsigned* const gf = flags + bg * 64;
    float cst = 0.f;

    for (int t = 0; t < T_; ++t) {
        // xp loads issued BEFORE the wait: HBM latency hides under the spin
        f16 xg0 = xp[((size_t)t * G_ + (0 * 1024 + nh)) * B_ + bglob];
        f16 xg1 = xp[((size_t)t * G_ + (1 * 1024 + nh)) * B_ + bglob];
        f16 xg2 = xp[((size_t)t * G_ + (2 * 1024 + nh)) * B_ + bglob];
        f16 xg3 = xp[((size_t)t * G_ + (3 * 1024 + nh)) * B_ + bglob];

        // wave 0 polls its group's 64 flags; waves 1-3 park at the barrier
        if (w == 0) {
            const unsigned tgt = (unsigned)(t + 1);
            while (true) {
                unsigned v = __hip_atomic_load(&gf[l], __ATOMIC_RELAXED, __HIP_MEMORY_SCOPE_AGENT);
                if (__all(v >= tgt)) break;
            }
        }
        __syncthreads();

        const int cur = t & 1;

        // A fragments: 8 x 16B coherent loads from LLC
        f16x8 af[8];
        {
            const char* pl = ab + (size_t)cur * BUFB + grp_ld;
            #pragma unroll
            for (int kk = 0; kk < 8; ++kk)
                asm volatile("global_load_dwordx4 %0, %1, off sc0 sc1"
                             : "=&v"(af[kk]) : "v"(pl + kk * 1024) : "memory");
        }
        asm volatile("s_waitcnt vmcnt(0)" ::: "memory");
        __builtin_amdgcn_sched_barrier(0);   // rule 18: pin MFMA after the wait

        f32x4_t acc[4];
        #pragma unroll
        for (int nt = 0; nt < 4; ++nt) acc[nt] = f32x4_t{0.f, 0.f, 0.f, 0.f};
        #pragma unroll
        for (int kk = 0; kk < 8; ++kk) {
            #pragma unroll
            for (int nt = 0; nt < 4; ++nt) {
                f16x8 bf = *(const f16x8*)(wlds + ((((w * 8 + kk) * 4 + nt) * 64 + l) << 3));
                acc[nt] = mfma16(af[kk], bf, acc[nt]);
            }
        }

        // cross-wave K-reduction via LDS
        {
            const int r0 = dh << 2;
            #pragma unroll
            for (int nt = 0; nt < 4; ++nt)
                #pragma unroll
                for (int j = 0; j < 4; ++j)
                    pacc[w][nt][r0 + j][l & 15] = acc[nt][j];
        }
        __syncthreads();

        float g0 = pacc[0][w][lb][0 * 4 + dh] + pacc[1][w][lb][0 * 4 + dh]
                 + pacc[2][w][lb][0 * 4 + dh] + pacc[3][w][lb][0 * 4 + dh] + (float)xg0;
        float g1 = pacc[0][w][lb][1 * 4 + dh] + pacc[1][w][lb][1 * 4 + dh]
                 + pacc[2][w][lb][1 * 4 + dh] + pacc[3][w][lb][1 * 4 + dh] + (float)xg1;
        float g2 = pacc[0][w][lb][2 * 4 + dh] + pacc[1][w][lb][2 * 4 + dh]
                 + pacc[2][w][lb][2 * 4 + dh] + pacc[3][w][lb][2 * 4 + dh] + (float)xg2;
        float g3 = pacc[0][w][lb][3 * 4 + dh] + pacc[1][w][lb][3 * 4 + dh]
                 + pacc[2][w][lb][3 * 4 + dh] + pacc[3][w][lb][3 * 4 + dh] + (float)xg3;

        float si = 1.f / (1.f + __expf(-g0));
        float tj = tanhf(g1);
        float sf = 1.f / (1.f + __expf(-(g2 + 1.f)));
        float so = 1.f / (1.f + __expf(-g3));
        cst = cst * sf + si * tj;
        float h = tanhf(cst) * so;

        out[((size_t)bglob * T_ + t) * N_ + nh] = h;

        // pack 4 h (dh=0..3) into one 8B slot -> next buffer (LLC, relaxed)
        {
            unsigned hu = (unsigned)__builtin_bit_cast(unsigned short, (f16)h);
            unsigned ot = __shfl_xor(hu, 16);
            unsigned dw = (dh & 1) ? ((ot & 0xffffu) | (hu << 16))
                                   : ((hu & 0xffffu) | (ot << 16));
            unsigned dw2 = __shfl_xor(dw, 32);
            if (dh == 0) {
                u64 val = (u64)dw | ((u64)dw2 << 32);
                __hip_atomic_store((u64*)(ab + (size_t)(cur ^ 1) * BUFB + grp_st), val,
                                   __ATOMIC_RELAXED, __HIP_MEMORY_SCOPE_AGENT);
            }
        }

        // hand-rolled release: ack all stores at LLC, then publish epoch.
        // NO fence instruction -> no buffer_wbl2 L2 writeback.
        asm volatile("s_waitcnt vmcnt(0)" ::: "memory");
        __syncthreads();
        if (tid == 0)
            __hip_atomic_store(&flags[wg], (unsigned)(t + 2),
                               __ATOMIC_RELAXED, __HIP_MEMORY_SCOPE_AGENT);
    }
}

// ---------------------------------------------------------------------------
extern "C" void kernel_launch(void* const* d_in, const int* in_sizes, int n_in,
                              void* d_out, int out_size, void* d_ws, size_t ws_size,
                              hipStream_t stream) {
    const float* x    = (const float*)d_in[0];
    const float* W    = (const float*)d_in[1];
    const float* bias = (const float*)d_in[2];
    float* out = (float*)d_out;

    char* ws = (char*)d_ws;
    f16*      WxT   = (f16*)ws;                          // dead after k_xproj
    f16*      Abuf  = (f16*)ws;                          // 262144 B (overlaps WxT)
    unsigned* flags = (unsigned*)(ws + 262144);          // 1024 B
    f16*      xp    = (f16*)(ws + ((size_t)4 << 20));    // 256 MB

    const size_t need = ((size_t)4 << 20) + ((size_t)1 << 28);
    if (ws_size < need) {
        hipMemsetAsync(d_out, 0, (size_t)out_size * sizeof(float), stream);
        return;
    }

    hipLaunchKernelGGL(k_transpose_wx, dim3(512), dim3(256), 0, stream, W, WxT);
    hipLaunchKernelGGL(k_xproj, dim3(512), dim3(256), 0, stream, x, WxT, bias, xp);

    hipMemsetAsync(flags, 0, 1024, stream);   // replay-deterministic epoch reset

    const f16* xp_c = xp;
    void* args[] = { (void*)&W, (void*)&xp_c, (void*)&Abuf, (void*)&flags, (void*)&out };
    hipError_t e = hipLaunchCooperativeKernel((void*)k_recur4, dim3(256), dim3(256),
                                              args, 0, stream);
    if (e != hipSuccess) {
        // 148 KB LDS -> 1 WG/CU, grid 256 == CU count: co-residency holds
        hipLaunchKernelGGL(k_recur4, dim3(256), dim3(256), 0, stream,
                           W, xp_c, Abuf, flags, out);
    }
}

// Round 6
// 2603.870 us; speedup vs baseline: 7.0404x; 1.1714x over previous
//
#include <hip/hip_runtime.h>

#define B_ 64
#define T_ 512
#define D_ 512
#define N_ 1024
#define G_ 4096   // 4*N

typedef _Float16 f16;
typedef __attribute__((ext_vector_type(8))) _Float16 f16x8;
typedef __attribute__((ext_vector_type(4))) _Float16 f16x4;
typedef __attribute__((ext_vector_type(4))) float f32x4_t;
typedef unsigned long long u64;
typedef __attribute__((ext_vector_type(4))) unsigned int u32x4;

static __device__ __forceinline__ f32x4_t mfma16(f16x8 a, f16x8 b, f32x4_t c) {
    return __builtin_amdgcn_mfma_f32_16x16x32_f16(a, b, c, 0, 0, 0);
}

// ---------------------------------------------------------------------------
// Phase 0: WxT[g][d] = (f16) W[d][g]   (validated R1)
// ---------------------------------------------------------------------------
__global__ __launch_bounds__(256) void k_transpose_wx(const float* __restrict__ W,
                                                      f16* __restrict__ WxT) {
    __shared__ float tile[64][65];
    int bx = blockIdx.x;
    int dt = bx >> 6, gt = bx & 63;
    int d0 = dt * 64, g0 = gt * 64;
    int tid = threadIdx.x;
    for (int e = tid; e < 4096; e += 256) {
        int r = e >> 6, c = e & 63;
        tile[r][c] = W[(size_t)(d0 + r) * G_ + (g0 + c)];
    }
    __syncthreads();
    for (int e = tid; e < 4096; e += 256) {
        int r = e >> 6, c = e & 63;
        WxT[(size_t)(g0 + r) * D_ + (d0 + c)] = (f16)tile[c][r];
    }
}

// ---------------------------------------------------------------------------
// Phase 1: xp[t][g][b] = (f16)( x@Wx + bias )   (validated R1)
// ---------------------------------------------------------------------------
__global__ __launch_bounds__(256, 2) void k_xproj(const float* __restrict__ x,
                                                  const f16* __restrict__ WxT,
                                                  const float* __restrict__ bias,
                                                  f16* __restrict__ xp) {
    __shared__ __align__(16) f16 alds[64 * 512];   // 64 KB
    int t = blockIdx.x;
    int tid = threadIdx.x;
    int w = tid >> 6, l = tid & 63;

    for (int ch = tid; ch < 4096; ch += 256) {
        int b  = ch >> 6;
        int d0 = (ch & 63) << 3;
        const float* px = x + ((size_t)b * T_ + t) * D_ + d0;
        float4 v0 = *(const float4*)px;
        float4 v1 = *(const float4*)(px + 4);
        f16x8 s;
        s[0] = (f16)v0.x; s[1] = (f16)v0.y; s[2] = (f16)v0.z; s[3] = (f16)v0.w;
        s[4] = (f16)v1.x; s[5] = (f16)v1.y; s[6] = (f16)v1.z; s[7] = (f16)v1.w;
        unsigned byteoff = ((unsigned)(b * 512 + d0) * 2u) ^ ((unsigned)(b & 7) << 4);
        *(f16x8*)((char*)alds + byteoff) = s;
    }
    __syncthreads();

    const int gw = w * 1024;
    const int qk = (l >> 4) << 3;
    const int cc = l & 15;

    for (int gtb = 0; gtb < 16; ++gtb) {
        f32x4_t acc[4][4];
        #pragma unroll
        for (int a = 0; a < 4; ++a)
            #pragma unroll
            for (int m = 0; m < 4; ++m) acc[a][m] = f32x4_t{0.f, 0.f, 0.f, 0.f};

        for (int ks = 0; ks < 16; ++ks) {
            f16x8 afr[4];
            #pragma unroll
            for (int mb = 0; mb < 4; ++mb) {
                int b = mb * 16 + cc;
                int d = ks * 32 + qk;
                unsigned byteoff = ((unsigned)(b * 512 + d) * 2u) ^ ((unsigned)(b & 7) << 4);
                afr[mb] = *(const f16x8*)((const char*)alds + byteoff);
            }
            #pragma unroll
            for (int gl = 0; gl < 4; ++gl) {
                int g = gw + (gtb * 4 + gl) * 16 + cc;
                f16x8 bfr = *(const f16x8*)(WxT + (size_t)g * D_ + ks * 32 + qk);
                #pragma unroll
                for (int mb = 0; mb < 4; ++mb)
                    acc[gl][mb] = mfma16(afr[mb], bfr, acc[gl][mb]);
            }
        }
        #pragma unroll
        for (int gl = 0; gl < 4; ++gl) {
            int g = gw + (gtb * 4 + gl) * 16 + cc;
            float bg = bias[g];
            #pragma unroll
            for (int mb = 0; mb < 4; ++mb) {
                int b0 = mb * 16 + ((l >> 4) << 2);
                f16x4 sv;
                sv[0] = (f16)(acc[gl][mb][0] + bg);
                sv[1] = (f16)(acc[gl][mb][1] + bg);
                sv[2] = (f16)(acc[gl][mb][2] + bg);
                sv[3] = (f16)(acc[gl][mb][3] + bg);
                *(f16x4*)(xp + ((size_t)t * G_ + g) * B_ + b0) = sv;
            }
        }
    }
}

// ---------------------------------------------------------------------------
// Phase 2: persistent recurrence, tag-in-data protocol (no flags, no fences).
// Slot = 8B = [2 x f16 h | u32 epoch tag], written as ONE u64 agent atomic
// (tear-proof). A-fragment (8 h for one (ks,lane)) = 32B = 4 slots:
//   [q0: h0 h1 tag | h2 h3 tag][q1: h4 h5 tag | h6 h7 tag]
// Consumer polls its own A-region until all tags == t+1; payload arrives with
// validity in the same load -> single LLC round trip per step.
// Anti-dep (buffer reuse at t+2) is safe: every producer is a consumer whose
// stores are sequenced after its loads (pacc barrier) -> 2-step slack.
// ---------------------------------------------------------------------------
__global__ __launch_bounds__(256, 1) void k_recur6(const float* __restrict__ W,
                                                   const f16* __restrict__ xp,
                                                   char* __restrict__ ab,
                                                   float* __restrict__ out) {
    __shared__ __align__(16) f16 wlds[65536];   // 128 KB [ks32][nt4][lane64][i8]
    __shared__ float pacc[4][4][16][17];        // [kwave][ntile][batch][c15+pad]

    const int wg  = blockIdx.x;
    const int tid = threadIdx.x;
    const int w   = tid >> 6;
    const int l   = tid & 63;
    const int bg  = wg >> 6;
    const int ci  = wg & 63;

    const int lb    = l & 15;
    const int dh    = l >> 4;
    const int nh    = ci * 16 + w * 4 + dh;
    const int bglob = bg * 16 + lb;

    // ---- stage Wh slice into LDS (B-fragment order, validated R3) ----
    for (int idx = tid; idx < 65536; idx += 256) {
        int gcl = idx & 63;
        int k   = idx >> 6;
        int ty  = gcl >> 4, c = gcl & 15;
        float wv = W[(size_t)(D_ + k) * G_ + ty * 1024 + ci * 16 + c];
        int ks = k >> 5, i = k & 7, kq = (k >> 3) & 3;
        int nt = c >> 2, dcl = c & 3;
        int lane = (kq << 4) | (ty << 2) | dcl;
        wlds[(((ks * 4 + nt) * 64 + lane) << 3) + i] = (f16)wv;
    }

    // ---- producer slot addressing (quad base col nq, 4 h per 2 slots) ----
    const int nq   = ci * 16 + w * 4;          // dh=0 base column of the quad
    const int ksq  = nq >> 5;
    const int lanq = (((nq & 31) >> 3) << 4) | lb;
    const size_t BUFB   = 262144;              // bytes per buffer copy
    const size_t st_off = (size_t)bg * 65536 + (size_t)(ksq * 64 + lanq) * 32
                        + (size_t)(w & 1) * 16 + (size_t)(dh >> 1) * 8;
    const bool   do_st  = ((dh & 1) == 0);     // lanes dh 0,2 store the halves

    // ---- consumer addressing: wave w reads k in [256w, 256w+256) ----
    const size_t ld_off = (size_t)bg * 65536 + (size_t)(w * 8 * 64 + l) * 32;

    // ---- init: h_0 = 0 with tag 1 into buf0 (buffer pre-memset to tag 0) ----
    if (do_st)
        __hip_atomic_store((u64*)(ab + st_off), (u64)1u << 32,
                           __ATOMIC_RELAXED, __HIP_MEMORY_SCOPE_AGENT);

    __syncthreads();   // wlds ready

    float cst = 0.f;

    for (int t = 0; t < T_; ++t) {
        // xp loads issued early (HBM latency hides under the poll)
        f16 xg0 = xp[((size_t)t * G_ + (0 * 1024 + nh)) * B_ + bglob];
        f16 xg1 = xp[((size_t)t * G_ + (1 * 1024 + nh)) * B_ + bglob];
        f16 xg2 = xp[((size_t)t * G_ + (2 * 1024 + nh)) * B_ + bglob];
        f16 xg3 = xp[((size_t)t * G_ + (3 * 1024 + nh)) * B_ + bglob];

        // ---- poll A-region until every slot carries tag t+1 ----
        u32x4 qa[8], qb[8];
        {
            const char* pb = ab + (size_t)(t & 1) * BUFB + ld_off;
            const unsigned tg = (unsigned)(t + 1);
            while (true) {
                #pragma unroll
                for (int kk = 0; kk < 8; ++kk) {
                    asm volatile("global_load_dwordx4 %0, %1, off sc0 sc1"
                                 : "=&v"(qa[kk]) : "v"(pb + kk * 2048) : "memory");
                    asm volatile("global_load_dwordx4 %0, %1, off sc0 sc1"
                                 : "=&v"(qb[kk]) : "v"(pb + kk * 2048 + 16) : "memory");
                }
                asm volatile("s_waitcnt vmcnt(0)" ::: "memory");
                bool ok = true;
                #pragma unroll
                for (int kk = 0; kk < 8; ++kk)
                    ok = ok && (qa[kk][1] == tg) && (qa[kk][3] == tg)
                            && (qb[kk][1] == tg) && (qb[kk][3] == tg);
                if (__all(ok)) break;
            }
        }
        __builtin_amdgcn_sched_barrier(0);   // rule 18: keep MFMA after the wait

        // ---- assemble fragments + MFMA ----
        f32x4_t acc[4];
        #pragma unroll
        for (int nt = 0; nt < 4; ++nt) acc[nt] = f32x4_t{0.f, 0.f, 0.f, 0.f};
        #pragma unroll
        for (int kk = 0; kk < 8; ++kk) {
            u32x4 av = { qa[kk][0], qa[kk][2], qb[kk][0], qb[kk][2] };
            f16x8 af = __builtin_bit_cast(f16x8, av);
            #pragma unroll
            for (int nt = 0; nt < 4; ++nt) {
                f16x8 bf = *(const f16x8*)(wlds + ((((w * 8 + kk) * 4 + nt) * 64 + l) << 3));
                acc[nt] = mfma16(af, bf, acc[nt]);
            }
        }

        // ---- cross-wave K-reduction via LDS ----
        {
            const int r0 = dh << 2;
            #pragma unroll
            for (int nt = 0; nt < 4; ++nt)
                #pragma unroll
                for (int j = 0; j < 4; ++j)
                    pacc[w][nt][r0 + j][l & 15] = acc[nt][j];
        }
        __syncthreads();

        float g0 = pacc[0][w][lb][0 * 4 + dh] + pacc[1][w][lb][0 * 4 + dh]
                 + pacc[2][w][lb][0 * 4 + dh] + pacc[3][w][lb][0 * 4 + dh] + (float)xg0;
        float g1 = pacc[0][w][lb][1 * 4 + dh] + pacc[1][w][lb][1 * 4 + dh]
                 + pacc[2][w][lb][1 * 4 + dh] + pacc[3][w][lb][1 * 4 + dh] + (float)xg1;
        float g2 = pacc[0][w][lb][2 * 4 + dh] + pacc[1][w][lb][2 * 4 + dh]
                 + pacc[2][w][lb][2 * 4 + dh] + pacc[3][w][lb][2 * 4 + dh] + (float)xg2;
        float g3 = pacc[0][w][lb][3 * 4 + dh] + pacc[1][w][lb][3 * 4 + dh]
                 + pacc[2][w][lb][3 * 4 + dh] + pacc[3][w][lb][3 * 4 + dh] + (float)xg3;

        float si = 1.f / (1.f + __expf(-g0));
        float tj = tanhf(g1);
        float sf = 1.f / (1.f + __expf(-(g2 + 1.f)));
        float so = 1.f / (1.f + __expf(-g3));
        cst = cst * sf + si * tj;
        float h = tanhf(cst) * so;

        // ---- publish h FIRST (critical path), tag rides with the data ----
        {
            unsigned hu = (unsigned)__builtin_bit_cast(unsigned short, (f16)h);
            unsigned ot = __shfl_xor(hu, 16);          // partner dh^1
            if (do_st && t < T_ - 1) {
                unsigned dw = (hu & 0xffffu) | (ot << 16);   // [h(dh)][h(dh+1)]
                u64 val = (u64)dw | ((u64)(unsigned)(t + 2) << 32);
                __hip_atomic_store((u64*)(ab + (size_t)((t + 1) & 1) * BUFB + st_off),
                                   val, __ATOMIC_RELAXED, __HIP_MEMORY_SCOPE_AGENT);
            }
        }

        out[((size_t)bglob * T_ + t) * N_ + nh] = h;

        __syncthreads();   // pacc anti-dependency for next step
    }
}

// ---------------------------------------------------------------------------
extern "C" void kernel_launch(void* const* d_in, const int* in_sizes, int n_in,
                              void* d_out, int out_size, void* d_ws, size_t ws_size,
                              hipStream_t stream) {
    const float* x    = (const float*)d_in[0];
    const float* W    = (const float*)d_in[1];
    const float* bias = (const float*)d_in[2];
    float* out = (float*)d_out;

    char* ws = (char*)d_ws;
    f16*  WxT  = (f16*)ws;                        // [0,4MB), dead after k_xproj
    char* Abuf = ws;                              // 512 KB, overlaps dead WxT
    f16*  xp   = (f16*)(ws + ((size_t)4 << 20));  // 256 MB

    const size_t need = ((size_t)4 << 20) + ((size_t)1 << 28);
    if (ws_size < need) {
        hipMemsetAsync(d_out, 0, (size_t)out_size * sizeof(float), stream);
        return;
    }

    hipLaunchKernelGGL(k_transpose_wx, dim3(512), dim3(256), 0, stream, W, WxT);
    hipLaunchKernelGGL(k_xproj, dim3(512), dim3(256), 0, stream, x, WxT, bias, xp);

    // zero all slot tags (buffer overlaps WxT -> must run after k_xproj);
    // re-executes on every graph replay -> deterministic protocol start.
    hipMemsetAsync(Abuf, 0, 2 * 262144, stream);

    const f16* xp_c = xp;
    void* args[] = { (void*)&W, (void*)&xp_c, (void*)&Abuf, (void*)&out };
    hipError_t e = hipLaunchCooperativeKernel((void*)k_recur6, dim3(256), dim3(256),
                                              args, 0, stream);
    if (e != hipSuccess) {
        // 145 KB LDS -> 1 WG/CU, grid 256 == CU count: co-residency holds
        hipLaunchKernelGGL(k_recur6, dim3(256), dim3(256), 0, stream,
                           W, xp_c, Abuf, out);
    }
}

// Round 7
// 2412.784 us; speedup vs baseline: 7.5979x; 1.0792x over previous
//
#include <hip/hip_runtime.h>

#define B_ 64
#define T_ 512
#define D_ 512
#define N_ 1024
#define G_ 4096   // 4*N

typedef _Float16 f16;
typedef __attribute__((ext_vector_type(8))) _Float16 f16x8;
typedef __attribute__((ext_vector_type(4))) _Float16 f16x4;
typedef __attribute__((ext_vector_type(4))) float f32x4_t;
typedef unsigned long long u64;
typedef __attribute__((ext_vector_type(4))) unsigned int u32x4;

static __device__ __forceinline__ f32x4_t mfma16(f16x8 a, f16x8 b, f32x4_t c) {
    return __builtin_amdgcn_mfma_f32_16x16x32_f16(a, b, c, 0, 0, 0);
}

// ---------------------------------------------------------------------------
// Phase 0: WxT[g][d] = (f16) W[d][g]   (validated R1)
// ---------------------------------------------------------------------------
__global__ __launch_bounds__(256) void k_transpose_wx(const float* __restrict__ W,
                                                      f16* __restrict__ WxT) {
    __shared__ float tile[64][65];
    int bx = blockIdx.x;
    int dt = bx >> 6, gt = bx & 63;
    int d0 = dt * 64, g0 = gt * 64;
    int tid = threadIdx.x;
    for (int e = tid; e < 4096; e += 256) {
        int r = e >> 6, c = e & 63;
        tile[r][c] = W[(size_t)(d0 + r) * G_ + (g0 + c)];
    }
    __syncthreads();
    for (int e = tid; e < 4096; e += 256) {
        int r = e >> 6, c = e & 63;
        WxT[(size_t)(g0 + r) * D_ + (d0 + c)] = (f16)tile[c][r];
    }
}

// ---------------------------------------------------------------------------
// Phase 1: xp[t][g][b] = (f16)( x@Wx + bias )   (validated R1)
// ---------------------------------------------------------------------------
__global__ __launch_bounds__(256, 2) void k_xproj(const float* __restrict__ x,
                                                  const f16* __restrict__ WxT,
                                                  const float* __restrict__ bias,
                                                  f16* __restrict__ xp) {
    __shared__ __align__(16) f16 alds[64 * 512];   // 64 KB
    int t = blockIdx.x;
    int tid = threadIdx.x;
    int w = tid >> 6, l = tid & 63;

    for (int ch = tid; ch < 4096; ch += 256) {
        int b  = ch >> 6;
        int d0 = (ch & 63) << 3;
        const float* px = x + ((size_t)b * T_ + t) * D_ + d0;
        float4 v0 = *(const float4*)px;
        float4 v1 = *(const float4*)(px + 4);
        f16x8 s;
        s[0] = (f16)v0.x; s[1] = (f16)v0.y; s[2] = (f16)v0.z; s[3] = (f16)v0.w;
        s[4] = (f16)v1.x; s[5] = (f16)v1.y; s[6] = (f16)v1.z; s[7] = (f16)v1.w;
        unsigned byteoff = ((unsigned)(b * 512 + d0) * 2u) ^ ((unsigned)(b & 7) << 4);
        *(f16x8*)((char*)alds + byteoff) = s;
    }
    __syncthreads();

    const int gw = w * 1024;
    const int qk = (l >> 4) << 3;
    const int cc = l & 15;

    for (int gtb = 0; gtb < 16; ++gtb) {
        f32x4_t acc[4][4];
        #pragma unroll
        for (int a = 0; a < 4; ++a)
            #pragma unroll
            for (int m = 0; m < 4; ++m) acc[a][m] = f32x4_t{0.f, 0.f, 0.f, 0.f};

        for (int ks = 0; ks < 16; ++ks) {
            f16x8 afr[4];
            #pragma unroll
            for (int mb = 0; mb < 4; ++mb) {
                int b = mb * 16 + cc;
                int d = ks * 32 + qk;
                unsigned byteoff = ((unsigned)(b * 512 + d) * 2u) ^ ((unsigned)(b & 7) << 4);
                afr[mb] = *(const f16x8*)((const char*)alds + byteoff);
            }
            #pragma unroll
            for (int gl = 0; gl < 4; ++gl) {
                int g = gw + (gtb * 4 + gl) * 16 + cc;
                f16x8 bfr = *(const f16x8*)(WxT + (size_t)g * D_ + ks * 32 + qk);
                #pragma unroll
                for (int mb = 0; mb < 4; ++mb)
                    acc[gl][mb] = mfma16(afr[mb], bfr, acc[gl][mb]);
            }
        }
        #pragma unroll
        for (int gl = 0; gl < 4; ++gl) {
            int g = gw + (gtb * 4 + gl) * 16 + cc;
            float bg = bias[g];
            #pragma unroll
            for (int mb = 0; mb < 4; ++mb) {
                int b0 = mb * 16 + ((l >> 4) << 2);
                f16x4 sv;
                sv[0] = (f16)(acc[gl][mb][0] + bg);
                sv[1] = (f16)(acc[gl][mb][1] + bg);
                sv[2] = (f16)(acc[gl][mb][2] + bg);
                sv[3] = (f16)(acc[gl][mb][3] + bg);
                *(f16x4*)(xp + ((size_t)t * G_ + g) * B_ + b0) = sv;
            }
        }
    }
}

// ---------------------------------------------------------------------------
// Phase 2: persistent recurrence, tag-in-data protocol (validated R6).
// R7 deltas: (1) xp loads + out stores NON-TEMPORAL -> the 384 MB of
// streaming traffic stops evicting the 512 KB Abuf from the LLC, so the
// h broadcast is served at LLC (not HBM) latency; (2) s_sleep backoff in
// the poll -> retry traffic drops ~5x, removing LLC congestion.
// ---------------------------------------------------------------------------
__global__ __launch_bounds__(256, 1) void k_recur7(const float* __restrict__ W,
                                                   const f16* __restrict__ xp,
                                                   char* __restrict__ ab,
                                                   float* __restrict__ out) {
    __shared__ __align__(16) f16 wlds[65536];   // 128 KB [ks32][nt4][lane64][i8]
    __shared__ float pacc[4][4][16][17];        // [kwave][ntile][batch][c15+pad]

    const int wg  = blockIdx.x;
    const int tid = threadIdx.x;
    const int w   = tid >> 6;
    const int l   = tid & 63;
    const int bg  = wg >> 6;
    const int ci  = wg & 63;

    const int lb    = l & 15;
    const int dh    = l >> 4;
    const int nh    = ci * 16 + w * 4 + dh;
    const int bglob = bg * 16 + lb;

    // ---- stage Wh slice into LDS (B-fragment order, validated R3) ----
    for (int idx = tid; idx < 65536; idx += 256) {
        int gcl = idx & 63;
        int k   = idx >> 6;
        int ty  = gcl >> 4, c = gcl & 15;
        float wv = W[(size_t)(D_ + k) * G_ + ty * 1024 + ci * 16 + c];
        int ks = k >> 5, i = k & 7, kq = (k >> 3) & 3;
        int nt = c >> 2, dcl = c & 3;
        int lane = (kq << 4) | (ty << 2) | dcl;
        wlds[(((ks * 4 + nt) * 64 + lane) << 3) + i] = (f16)wv;
    }

    // ---- producer slot addressing ----
    const int nq   = ci * 16 + w * 4;
    const int ksq  = nq >> 5;
    const int lanq = (((nq & 31) >> 3) << 4) | lb;
    const size_t BUFB   = 262144;
    const size_t st_off = (size_t)bg * 65536 + (size_t)(ksq * 64 + lanq) * 32
                        + (size_t)(w & 1) * 16 + (size_t)(dh >> 1) * 8;
    const bool   do_st  = ((dh & 1) == 0);

    // ---- consumer addressing: wave w reads k in [256w, 256w+256) ----
    const size_t ld_off = (size_t)bg * 65536 + (size_t)(w * 8 * 64 + l) * 32;

    // ---- init: h_0 = 0 with tag 1 into buf0 (tags pre-memset to 0) ----
    if (do_st)
        __hip_atomic_store((u64*)(ab + st_off), (u64)1u << 32,
                           __ATOMIC_RELAXED, __HIP_MEMORY_SCOPE_AGENT);

    __syncthreads();   // wlds ready

    float cst = 0.f;

    for (int t = 0; t < T_; ++t) {
        // xp loads: non-temporal (no LLC pollution), issued early so HBM
        // latency hides under the poll
        const unsigned short* xpp = (const unsigned short*)xp
                                  + (size_t)t * G_ * B_ + bglob;
        f16 xg0 = __builtin_bit_cast(f16, __builtin_nontemporal_load(xpp + (size_t)(0 * 1024 + nh) * B_));
        f16 xg1 = __builtin_bit_cast(f16, __builtin_nontemporal_load(xpp + (size_t)(1 * 1024 + nh) * B_));
        f16 xg2 = __builtin_bit_cast(f16, __builtin_nontemporal_load(xpp + (size_t)(2 * 1024 + nh) * B_));
        f16 xg3 = __builtin_bit_cast(f16, __builtin_nontemporal_load(xpp + (size_t)(3 * 1024 + nh) * B_));

        // ---- poll A-region until every slot carries tag t+1 ----
        u32x4 qa[8], qb[8];
        {
            const char* pb = ab + (size_t)(t & 1) * BUFB + ld_off;
            const unsigned tg = (unsigned)(t + 1);
            while (true) {
                #pragma unroll
                for (int kk = 0; kk < 8; ++kk) {
                    asm volatile("global_load_dwordx4 %0, %1, off sc0 sc1"
                                 : "=&v"(qa[kk]) : "v"(pb + kk * 2048) : "memory");
                    asm volatile("global_load_dwordx4 %0, %1, off sc0 sc1"
                                 : "=&v"(qb[kk]) : "v"(pb + kk * 2048 + 16) : "memory");
                }
                asm volatile("s_waitcnt vmcnt(0)" ::: "memory");
                bool ok = true;
                #pragma unroll
                for (int kk = 0; kk < 8; ++kk)
                    ok = ok && (qa[kk][1] == tg) && (qa[kk][3] == tg)
                            && (qb[kk][1] == tg) && (qb[kk][3] == tg);
                if (__all(ok)) break;
                __builtin_amdgcn_s_sleep(2);   // backoff: cut retry congestion
            }
        }
        __builtin_amdgcn_sched_barrier(0);   // rule 18: keep MFMA after the wait

        // ---- assemble fragments + MFMA ----
        f32x4_t acc[4];
        #pragma unroll
        for (int nt = 0; nt < 4; ++nt) acc[nt] = f32x4_t{0.f, 0.f, 0.f, 0.f};
        #pragma unroll
        for (int kk = 0; kk < 8; ++kk) {
            u32x4 av = { qa[kk][0], qa[kk][2], qb[kk][0], qb[kk][2] };
            f16x8 af = __builtin_bit_cast(f16x8, av);
            #pragma unroll
            for (int nt = 0; nt < 4; ++nt) {
                f16x8 bf = *(const f16x8*)(wlds + ((((w * 8 + kk) * 4 + nt) * 64 + l) << 3));
                acc[nt] = mfma16(af, bf, acc[nt]);
            }
        }

        // ---- cross-wave K-reduction via LDS ----
        {
            const int r0 = dh << 2;
            #pragma unroll
            for (int nt = 0; nt < 4; ++nt)
                #pragma unroll
                for (int j = 0; j < 4; ++j)
                    pacc[w][nt][r0 + j][l & 15] = acc[nt][j];
        }
        __syncthreads();

        float g0 = pacc[0][w][lb][0 * 4 + dh] + pacc[1][w][lb][0 * 4 + dh]
                 + pacc[2][w][lb][0 * 4 + dh] + pacc[3][w][lb][0 * 4 + dh] + (float)xg0;
        float g1 = pacc[0][w][lb][1 * 4 + dh] + pacc[1][w][lb][1 * 4 + dh]
                 + pacc[2][w][lb][1 * 4 + dh] + pacc[3][w][lb][1 * 4 + dh] + (float)xg1;
        float g2 = pacc[0][w][lb][2 * 4 + dh] + pacc[1][w][lb][2 * 4 + dh]
                 + pacc[2][w][lb][2 * 4 + dh] + pacc[3][w][lb][2 * 4 + dh] + (float)xg2;
        float g3 = pacc[0][w][lb][3 * 4 + dh] + pacc[1][w][lb][3 * 4 + dh]
                 + pacc[2][w][lb][3 * 4 + dh] + pacc[3][w][lb][3 * 4 + dh] + (float)xg3;

        float si = 1.f / (1.f + __expf(-g0));
        float tj = tanhf(g1);
        float sf = 1.f / (1.f + __expf(-(g2 + 1.f)));
        float so = 1.f / (1.f + __expf(-g3));
        cst = cst * sf + si * tj;
        float h = tanhf(cst) * so;

        // ---- publish h FIRST (critical path), tag rides with the data ----
        {
            unsigned hu = (unsigned)__builtin_bit_cast(unsigned short, (f16)h);
            unsigned ot = __shfl_xor(hu, 16);          // partner dh^1
            if (do_st && t < T_ - 1) {
                unsigned dw = (hu & 0xffffu) | (ot << 16);
                u64 val = (u64)dw | ((u64)(unsigned)(t + 2) << 32);
                __hip_atomic_store((u64*)(ab + (size_t)((t + 1) & 1) * BUFB + st_off),
                                   val, __ATOMIC_RELAXED, __HIP_MEMORY_SCOPE_AGENT);
            }
        }

        // out store: non-temporal (write-once stream, keep LLC for Abuf)
        __builtin_nontemporal_store(h, &out[((size_t)bglob * T_ + t) * N_ + nh]);

        __syncthreads();   // pacc anti-dependency for next step
    }
}

// ---------------------------------------------------------------------------
extern "C" void kernel_launch(void* const* d_in, const int* in_sizes, int n_in,
                              void* d_out, int out_size, void* d_ws, size_t ws_size,
                              hipStream_t stream) {
    const float* x    = (const float*)d_in[0];
    const float* W    = (const float*)d_in[1];
    const float* bias = (const float*)d_in[2];
    float* out = (float*)d_out;

    char* ws = (char*)d_ws;
    f16*  WxT  = (f16*)ws;                        // [0,4MB), dead after k_xproj
    char* Abuf = ws;                              // 512 KB, overlaps dead WxT
    f16*  xp   = (f16*)(ws + ((size_t)4 << 20));  // 256 MB

    const size_t need = ((size_t)4 << 20) + ((size_t)1 << 28);
    if (ws_size < need) {
        hipMemsetAsync(d_out, 0, (size_t)out_size * sizeof(float), stream);
        return;
    }

    hipLaunchKernelGGL(k_transpose_wx, dim3(512), dim3(256), 0, stream, W, WxT);
    hipLaunchKernelGGL(k_xproj, dim3(512), dim3(256), 0, stream, x, WxT, bias, xp);

    // zero all slot tags (region overlaps WxT -> must run after k_xproj);
    // re-executes on every graph replay -> deterministic protocol start.
    // Side effect: pre-warms the Abuf lines into the LLC.
    hipMemsetAsync(Abuf, 0, 2 * 262144, stream);

    const f16* xp_c = xp;
    void* args[] = { (void*)&W, (void*)&xp_c, (void*)&Abuf, (void*)&out };
    hipError_t e = hipLaunchCooperativeKernel((void*)k_recur7, dim3(256), dim3(256),
                                              args, 0, stream);
    if (e != hipSuccess) {
        // 145 KB LDS -> 1 WG/CU, grid 256 == CU count: co-residency holds
        hipLaunchKernelGGL(k_recur7, dim3(256), dim3(256), 0, stream,
                           W, xp_c, Abuf, out);
    }
}

// Round 8
// 2242.004 us; speedup vs baseline: 8.1767x; 1.0762x over previous
//
#include <hip/hip_runtime.h>

#define B_ 64
#define T_ 512
#define D_ 512
#define N_ 1024
#define G_ 4096   // 4*N

typedef _Float16 f16;
typedef __attribute__((ext_vector_type(8))) _Float16 f16x8;
typedef __attribute__((ext_vector_type(4))) _Float16 f16x4;
typedef __attribute__((ext_vector_type(4))) float f32x4_t;
typedef unsigned long long u64;

static __device__ __forceinline__ f32x4_t mfma16(f16x8 a, f16x8 b, f32x4_t c) {
    return __builtin_amdgcn_mfma_f32_16x16x32_f16(a, b, c, 0, 0, 0);
}

// workspace map (all inside first 4MB, overlapping dead WxT)
#define PAYB   131072        // one payload buffer copy: [bg4][32KB]
#define OFF_TAG 0x60000      // 3*PAYB = 0x60000; tags: 4*256 u32 = 4KB

// ---------------------------------------------------------------------------
// Phase 0: WxT[g][d] = (f16) W[d][g]   (validated R1)
// ---------------------------------------------------------------------------
__global__ __launch_bounds__(256) void k_transpose_wx(const float* __restrict__ W,
                                                      f16* __restrict__ WxT) {
    __shared__ float tile[64][65];
    int bx = blockIdx.x;
    int dt = bx >> 6, gt = bx & 63;
    int d0 = dt * 64, g0 = gt * 64;
    int tid = threadIdx.x;
    for (int e = tid; e < 4096; e += 256) {
        int r = e >> 6, c = e & 63;
        tile[r][c] = W[(size_t)(d0 + r) * G_ + (g0 + c)];
    }
    __syncthreads();
    for (int e = tid; e < 4096; e += 256) {
        int r = e >> 6, c = e & 63;
        WxT[(size_t)(g0 + r) * D_ + (d0 + c)] = (f16)tile[c][r];
    }
}

// ---------------------------------------------------------------------------
// Phase 1: xp[t][g][b] = (f16)( x@Wx + bias )   (validated R1)
// ---------------------------------------------------------------------------
__global__ __launch_bounds__(256, 2) void k_xproj(const float* __restrict__ x,
                                                  const f16* __restrict__ WxT,
                                                  const float* __restrict__ bias,
                                                  f16* __restrict__ xp) {
    __shared__ __align__(16) f16 alds[64 * 512];   // 64 KB
    int t = blockIdx.x;
    int tid = threadIdx.x;
    int w = tid >> 6, l = tid & 63;

    for (int ch = tid; ch < 4096; ch += 256) {
        int b  = ch >> 6;
        int d0 = (ch & 63) << 3;
        const float* px = x + ((size_t)b * T_ + t) * D_ + d0;
        float4 v0 = *(const float4*)px;
        float4 v1 = *(const float4*)(px + 4);
        f16x8 s;
        s[0] = (f16)v0.x; s[1] = (f16)v0.y; s[2] = (f16)v0.z; s[3] = (f16)v0.w;
        s[4] = (f16)v1.x; s[5] = (f16)v1.y; s[6] = (f16)v1.z; s[7] = (f16)v1.w;
        unsigned byteoff = ((unsigned)(b * 512 + d0) * 2u) ^ ((unsigned)(b & 7) << 4);
        *(f16x8*)((char*)alds + byteoff) = s;
    }
    __syncthreads();

    const int gw = w * 1024;
    const int qk = (l >> 4) << 3;
    const int cc = l & 15;

    for (int gtb = 0; gtb < 16; ++gtb) {
        f32x4_t acc[4][4];
        #pragma unroll
        for (int a = 0; a < 4; ++a)
            #pragma unroll
            for (int m = 0; m < 4; ++m) acc[a][m] = f32x4_t{0.f, 0.f, 0.f, 0.f};

        for (int ks = 0; ks < 16; ++ks) {
            f16x8 afr[4];
            #pragma unroll
            for (int mb = 0; mb < 4; ++mb) {
                int b = mb * 16 + cc;
                int d = ks * 32 + qk;
                unsigned byteoff = ((unsigned)(b * 512 + d) * 2u) ^ ((unsigned)(b & 7) << 4);
                afr[mb] = *(const f16x8*)((const char*)alds + byteoff);
            }
            #pragma unroll
            for (int gl = 0; gl < 4; ++gl) {
                int g = gw + (gtb * 4 + gl) * 16 + cc;
                f16x8 bfr = *(const f16x8*)(WxT + (size_t)g * D_ + ks * 32 + qk);
                #pragma unroll
                for (int mb = 0; mb < 4; ++mb)
                    acc[gl][mb] = mfma16(afr[mb], bfr, acc[gl][mb]);
            }
        }
        #pragma unroll
        for (int gl = 0; gl < 4; ++gl) {
            int g = gw + (gtb * 4 + gl) * 16 + cc;
            float bg = bias[g];
            #pragma unroll
            for (int mb = 0; mb < 4; ++mb) {
                int b0 = mb * 16 + ((l >> 4) << 2);
                f16x4 sv;
                sv[0] = (f16)(acc[gl][mb][0] + bg);
                sv[1] = (f16)(acc[gl][mb][1] + bg);
                sv[2] = (f16)(acc[gl][mb][2] + bg);
                sv[3] = (f16)(acc[gl][mb][3] + bg);
                *(f16x4*)(xp + ((size_t)t * G_ + g) * B_ + b0) = sv;
            }
        }
    }
}

// ---------------------------------------------------------------------------
// Phase 2: persistent recurrence. R8 protocol:
//  - payload: pure h slots (8B = 4 cols x 1 batch), TRIPLE-buffered.
//  - per-producer-WAVE tag: 16 payload stores -> s_waitcnt vmcnt(0) (wave-
//    wide release, no fence/no syncthreads) -> lane0 stores tag = t+2.
//  - consumer wave polls its 64 producer-wave tags (256 B/round, 64x less
//    poll bandwidth than R7's tag-in-data), then loads payload ONCE.
//  - monotone tag >= t+1 + triple buffer: writer of buf[t%3] (at step t+2)
//    observed tags >= t+3 => 2-hop closure => all step-t reads done. Safe
//    under arbitrary 1-step skew (fixes R6/R7's latent exact-match hazard).
// ---------------------------------------------------------------------------
__global__ __launch_bounds__(256, 1) void k_recur8(const float* __restrict__ W,
                                                   const f16* __restrict__ xp,
                                                   char* __restrict__ wsb,
                                                   float* __restrict__ out) {
    __shared__ __align__(16) f16 wlds[65536];   // 128 KB [ks32][nt4][lane64][i8]
    __shared__ float pacc[4][4][16][17];        // [kwave][ntile][batch][c15+pad]

    const int wg  = blockIdx.x;
    const int tid = threadIdx.x;
    const int w   = tid >> 6;
    const int l   = tid & 63;
    const int bg  = wg >> 6;
    const int ci  = wg & 63;

    const int lb    = l & 15;
    const int dh    = l >> 4;
    const int nh    = ci * 16 + w * 4 + dh;
    const int bglob = bg * 16 + lb;

    char*     const pay  = wsb;                      // 3 x 128 KB
    unsigned* const tags = (unsigned*)(wsb + OFF_TAG);

    // ---- stage Wh slice into LDS (B-fragment order, validated R3) ----
    for (int idx = tid; idx < 65536; idx += 256) {
        int gcl = idx & 63;
        int k   = idx >> 6;
        int ty  = gcl >> 4, c = gcl & 15;
        float wv = W[(size_t)(D_ + k) * G_ + ty * 1024 + ci * 16 + c];
        int ks = k >> 5, i = k & 7, kq = (k >> 3) & 3;
        int nt = c >> 2, dcl = c & 3;
        int lane = (kq << 4) | (ty << 2) | dcl;
        wlds[(((ks * 4 + nt) * 64 + lane) << 3) + i] = (f16)wv;
    }

    // ---- producer addressing: quad (ci, w, lb) -> cols nq..nq+3, batch lb ----
    const int nq  = ci * 16 + w * 4;
    const int ksq = nq >> 5;
    const int q8  = (nq & 31) >> 3;
    const size_t st_off = (size_t)bg * 32768
                        + ((size_t)(ksq * 64 + q8 * 16 + lb) << 4)
                        + (size_t)(w & 1) * 8;
    const bool do_st = (dh == 0);

    // ---- consumer addressing: wave w reads k in [256w, 256w+256) ----
    const size_t ld_off = (size_t)bg * 32768 + ((size_t)(w * 8 * 64 + l) << 4);

    // tag pointers: producer (ci, w) publishes; consumer lane l watches 64w+l
    unsigned* const tag_st = tags + (bg * 256 + ci * 4 + w);
    unsigned* const tag_ld = tags + (bg * 256 + w * 64 + l);

    // ---- init: zero payload buf0 (h_0 = 0), release, tag = 1 ----
    if (do_st)
        __hip_atomic_store((u64*)(pay + st_off), 0ull,
                           __ATOMIC_RELAXED, __HIP_MEMORY_SCOPE_AGENT);
    asm volatile("s_waitcnt vmcnt(0)" ::: "memory");
    if (l == 0)
        __hip_atomic_store(tag_st, 1u, __ATOMIC_RELAXED, __HIP_MEMORY_SCOPE_AGENT);

    __syncthreads();   // wlds ready

    float cst = 0.f;
    int cur = 0, nxt = 1;

    for (int t = 0; t < T_; ++t) {
        // xp loads: non-temporal, issued early (HBM latency hides under poll)
        const unsigned short* xpp = (const unsigned short*)xp
                                  + (size_t)t * G_ * B_ + bglob;
        f16 xg0 = __builtin_bit_cast(f16, __builtin_nontemporal_load(xpp + (size_t)(0 * 1024 + nh) * B_));
        f16 xg1 = __builtin_bit_cast(f16, __builtin_nontemporal_load(xpp + (size_t)(1 * 1024 + nh) * B_));
        f16 xg2 = __builtin_bit_cast(f16, __builtin_nontemporal_load(xpp + (size_t)(2 * 1024 + nh) * B_));
        f16 xg3 = __builtin_bit_cast(f16, __builtin_nontemporal_load(xpp + (size_t)(3 * 1024 + nh) * B_));

        // ---- poll 64 producer-wave tags (256 B/wave/round) ----
        {
            const unsigned tgt = (unsigned)(t + 1);
            while (true) {
                unsigned v = __hip_atomic_load(tag_ld, __ATOMIC_RELAXED,
                                               __HIP_MEMORY_SCOPE_AGENT);
                if (__all(v >= tgt)) break;
                __builtin_amdgcn_s_sleep(1);
            }
        }

        // ---- payload: 8 x 16B coherent loads, once ----
        f16x8 af[8];
        {
            const char* pl = pay + (size_t)cur * PAYB + ld_off;
            #pragma unroll
            for (int kk = 0; kk < 8; ++kk)
                asm volatile("global_load_dwordx4 %0, %1, off sc0 sc1"
                             : "=&v"(af[kk]) : "v"(pl + kk * 1024) : "memory");
        }
        asm volatile("s_waitcnt vmcnt(0)" ::: "memory");
        __builtin_amdgcn_sched_barrier(0);   // rule 18: keep MFMA after the wait

        f32x4_t acc[4];
        #pragma unroll
        for (int nt = 0; nt < 4; ++nt) acc[nt] = f32x4_t{0.f, 0.f, 0.f, 0.f};
        #pragma unroll
        for (int kk = 0; kk < 8; ++kk) {
            #pragma unroll
            for (int nt = 0; nt < 4; ++nt) {
                f16x8 bf = *(const f16x8*)(wlds + ((((w * 8 + kk) * 4 + nt) * 64 + l) << 3));
                acc[nt] = mfma16(af[kk], bf, acc[nt]);
            }
        }

        // ---- cross-wave K-reduction via LDS ----
        {
            const int r0 = dh << 2;
            #pragma unroll
            for (int nt = 0; nt < 4; ++nt)
                #pragma unroll
                for (int j = 0; j < 4; ++j)
                    pacc[w][nt][r0 + j][l & 15] = acc[nt][j];
        }
        __syncthreads();

        float g0 = pacc[0][w][lb][0 * 4 + dh] + pacc[1][w][lb][0 * 4 + dh]
                 + pacc[2][w][lb][0 * 4 + dh] + pacc[3][w][lb][0 * 4 + dh] + (float)xg0;
        float g1 = pacc[0][w][lb][1 * 4 + dh] + pacc[1][w][lb][1 * 4 + dh]
                 + pacc[2][w][lb][1 * 4 + dh] + pacc[3][w][lb][1 * 4 + dh] + (float)xg1;
        float g2 = pacc[0][w][lb][2 * 4 + dh] + pacc[1][w][lb][2 * 4 + dh]
                 + pacc[2][w][lb][2 * 4 + dh] + pacc[3][w][lb][2 * 4 + dh] + (float)xg2;
        float g3 = pacc[0][w][lb][3 * 4 + dh] + pacc[1][w][lb][3 * 4 + dh]
                 + pacc[2][w][lb][3 * 4 + dh] + pacc[3][w][lb][3 * 4 + dh] + (float)xg3;

        float si = 1.f / (1.f + __expf(-g0));
        float tj = tanhf(g1);
        float sf = 1.f / (1.f + __expf(-(g2 + 1.f)));
        float so = 1.f / (1.f + __expf(-g3));
        cst = cst * sf + si * tj;
        float h = tanhf(cst) * so;

        // ---- publish: payload stores -> wave release -> wave tag ----
        {
            unsigned hu = (unsigned)__builtin_bit_cast(unsigned short, (f16)h);
            unsigned ot = __shfl_xor(hu, 16);
            unsigned dw = (dh & 1) ? ((ot & 0xffffu) | (hu << 16))
                                   : ((hu & 0xffffu) | (ot << 16));
            unsigned dw2 = __shfl_xor(dw, 32);
            if (do_st && t < T_ - 1) {
                u64 val = (u64)dw | ((u64)dw2 << 32);
                __hip_atomic_store((u64*)(pay + (size_t)nxt * PAYB + st_off), val,
                                   __ATOMIC_RELAXED, __HIP_MEMORY_SCOPE_AGENT);
            }
        }
        asm volatile("s_waitcnt vmcnt(0)" ::: "memory");   // payload acked at LLC
        if (l == 0 && t < T_ - 1)
            __hip_atomic_store(tag_st, (unsigned)(t + 2),
                               __ATOMIC_RELAXED, __HIP_MEMORY_SCOPE_AGENT);

        // out store off the critical path (non-temporal stream)
        __builtin_nontemporal_store(h, &out[((size_t)bglob * T_ + t) * N_ + nh]);

        __syncthreads();   // pacc anti-dependency for next step
        cur = nxt;
        nxt = (nxt == 2) ? 0 : nxt + 1;
    }
}

// ---------------------------------------------------------------------------
extern "C" void kernel_launch(void* const* d_in, const int* in_sizes, int n_in,
                              void* d_out, int out_size, void* d_ws, size_t ws_size,
                              hipStream_t stream) {
    const float* x    = (const float*)d_in[0];
    const float* W    = (const float*)d_in[1];
    const float* bias = (const float*)d_in[2];
    float* out = (float*)d_out;

    char* ws = (char*)d_ws;
    f16*  WxT = (f16*)ws;                         // [0,4MB), dead after k_xproj
    f16*  xp  = (f16*)(ws + ((size_t)4 << 20));   // 256 MB

    const size_t need = ((size_t)4 << 20) + ((size_t)1 << 28);
    if (ws_size < need) {
        hipMemsetAsync(d_out, 0, (size_t)out_size * sizeof(float), stream);
        return;
    }

    hipLaunchKernelGGL(k_transpose_wx, dim3(512), dim3(256), 0, stream, W, WxT);
    hipLaunchKernelGGL(k_xproj, dim3(512), dim3(256), 0, stream, x, WxT, bias, xp);

    // zero the tag array (region overlaps dead WxT -> must run after k_xproj);
    // re-executes on every graph replay -> deterministic protocol start.
    hipMemsetAsync(ws + OFF_TAG, 0, 4096, stream);

    const f16* xp_c = xp;
    void* args[] = { (void*)&W, (void*)&xp_c, (void*)&ws, (void*)&out };
    hipError_t e = hipLaunchCooperativeKernel((void*)k_recur8, dim3(256), dim3(256),
                                              args, 0, stream);
    if (e != hipSuccess) {
        // 145 KB LDS -> 1 WG/CU, grid 256 == CU count: co-residency holds
        hipLaunchKernelGGL(k_recur8, dim3(256), dim3(256), 0, stream,
                           W, xp_c, ws, out);
    }
}